// Round 1
// baseline (2360.724 us; speedup 1.0000x reference)
//
#include <hip/hip_runtime.h>
#include <math.h>

#define CCH   256   // channels
#define DQK   32    // C/8
#define NPIX  4096  // H*W
#define BATCH 4

// ---------------- QK projection: q[b][d][n], k[b][d][n] ----------------
__global__ __launch_bounds__(256) void qk_kernel(
    const float* __restrict__ x,
    const float* __restrict__ Wq, const float* __restrict__ bq,
    const float* __restrict__ Wk, const float* __restrict__ bk,
    float* __restrict__ q_ws, float* __restrict__ k_ws)
{
    __shared__ float w_lds[16 * 256];
    const int t = threadIdx.x;
    const int ntile = blockIdx.x;   // 16 tiles of 256 pixels
    const int dtile = blockIdx.y;   // 0,1 -> q rows 0..31 ; 2,3 -> k rows 0..31
    const int b = blockIdx.z;
    const bool is_q = (dtile < 2);
    const int row0 = (dtile & 1) * 16;
    const float* W    = is_q ? Wq : Wk;
    const float* bias = is_q ? bq : bk;
    float* dst        = is_q ? q_ws : k_ws;

    #pragma unroll
    for (int dd = 0; dd < 16; ++dd)
        w_lds[dd * 256 + t] = W[(size_t)(row0 + dd) * CCH + t];
    __syncthreads();

    const int n = ntile * 256 + t;
    const float* xb = x + (size_t)b * CCH * NPIX + n;
    float acc[16];
    #pragma unroll
    for (int dd = 0; dd < 16; ++dd) acc[dd] = 0.f;
    for (int c = 0; c < CCH; ++c) {
        float xv = xb[(size_t)c * NPIX];
        #pragma unroll
        for (int dd = 0; dd < 16; ++dd)
            acc[dd] += w_lds[dd * 256 + c] * xv;
    }
    #pragma unroll
    for (int dd = 0; dd < 16; ++dd)
        dst[((size_t)b * DQK + row0 + dd) * NPIX + n] = acc[dd] + bias[row0 + dd];
}

// ---------------- V projection, transposed: v_t[b][n][c] ----------------
__global__ __launch_bounds__(256) void v_kernel(
    const float* __restrict__ x,
    const float* __restrict__ Wv, const float* __restrict__ bv,
    float* __restrict__ v_t)
{
    __shared__ float w_lds[16 * 256];
    const int t = threadIdx.x;
    const int ntile = blockIdx.x;   // 16
    const int ctile = blockIdx.y;   // 16 tiles of 16 output channels
    const int b = blockIdx.z;
    const int c0 = ctile * 16;

    #pragma unroll
    for (int dd = 0; dd < 16; ++dd)
        w_lds[dd * 256 + t] = Wv[(size_t)(c0 + dd) * CCH + t];
    __syncthreads();

    const int n = ntile * 256 + t;
    const float* xb = x + (size_t)b * CCH * NPIX + n;
    float acc[16];
    #pragma unroll
    for (int dd = 0; dd < 16; ++dd) acc[dd] = 0.f;
    for (int cc = 0; cc < CCH; ++cc) {
        float xv = xb[(size_t)cc * NPIX];
        #pragma unroll
        for (int dd = 0; dd < 16; ++dd)
            acc[dd] += w_lds[dd * 256 + cc] * xv;
    }
    float* vt = v_t + ((size_t)b * NPIX + n) * CCH + c0;
    #pragma unroll
    for (int j = 0; j < 4; ++j) {
        float4 o;
        o.x = acc[4 * j + 0] + bv[c0 + 4 * j + 0];
        o.y = acc[4 * j + 1] + bv[c0 + 4 * j + 1];
        o.z = acc[4 * j + 2] + bv[c0 + 4 * j + 2];
        o.w = acc[4 * j + 3] + bv[c0 + 4 * j + 3];
        *(float4*)&vt[4 * j] = o;
    }
}

// ---------------- flash attention + residual ----------------
// block = 256 threads, handles (batch b, 32 query rows). Loops over 64-col KV tiles.
__global__ __launch_bounds__(256) void attn_kernel(
    const float* __restrict__ q_ws, const float* __restrict__ k_ws,
    const float* __restrict__ v_t, const float* __restrict__ x,
    float* __restrict__ out)
{
    __shared__ float q_lds[32 * 36];       // [i][d], pad stride 36 (16B-aligned rows)
    __shared__ float p_lds[32 * 64];       // [i][j]
    __shared__ float alpha_lds[32];
    __shared__ float l_lds[32];
    __shared__ float o_lds[256 * 33];      // [c][i], pad 33

    const int t    = threadIdx.x;
    const int lane = t & 63;
    const int wg   = t >> 6;               // wave 0..3, handles rows wg*8..wg*8+7
    const int i0   = blockIdx.x * 32;
    const int b    = blockIdx.y;

    // load q tile (transposed to [i][d])
    {
        const int i = t & 31;
        const int dbase = t >> 5;          // 0..7
        #pragma unroll
        for (int r = 0; r < 4; ++r) {
            int d = r * 8 + dbase;
            q_lds[i * 36 + d] = q_ws[((size_t)b * DQK + d) * NPIX + i0 + i];
        }
    }
    __syncthreads();

    float m_i[8], l_i[8];
    #pragma unroll
    for (int ii = 0; ii < 8; ++ii) { m_i[ii] = -INFINITY; l_i[ii] = 0.f; }
    float acc[32];
    #pragma unroll
    for (int ii = 0; ii < 32; ++ii) acc[ii] = 0.f;

    for (int j0 = 0; j0 < NPIX; j0 += 64) {
        // ---- scores + online softmax (lane = j within tile) ----
        float kreg[32];
        #pragma unroll
        for (int d = 0; d < 32; ++d)
            kreg[d] = k_ws[((size_t)b * DQK + d) * NPIX + j0 + lane];

        float p[8], alpha[8];
        #pragma unroll
        for (int ii = 0; ii < 8; ++ii) {
            const int i = wg * 8 + ii;
            float s = 0.f;
            #pragma unroll
            for (int d4 = 0; d4 < 8; ++d4) {
                float4 qv = *(const float4*)&q_lds[i * 36 + d4 * 4];
                s += qv.x * kreg[d4 * 4 + 0] + qv.y * kreg[d4 * 4 + 1]
                   + qv.z * kreg[d4 * 4 + 2] + qv.w * kreg[d4 * 4 + 3];
            }
            float tm = s;
            #pragma unroll
            for (int off = 32; off >= 1; off >>= 1)
                tm = fmaxf(tm, __shfl_xor(tm, off));
            float m_new = fmaxf(m_i[ii], tm);
            float pe = __builtin_exp2f((s - m_new) * 1.44269504f);
            float a  = __builtin_exp2f((m_i[ii] - m_new) * 1.44269504f);
            float rs = pe;
            #pragma unroll
            for (int off = 32; off >= 1; off >>= 1)
                rs += __shfl_xor(rs, off);
            l_i[ii] = l_i[ii] * a + rs;
            m_i[ii] = m_new;
            p[ii] = pe; alpha[ii] = a;
        }
        #pragma unroll
        for (int ii = 0; ii < 8; ++ii)
            p_lds[(wg * 8 + ii) * 64 + lane] = p[ii];
        if (lane == 0) {
            #pragma unroll
            for (int ii = 0; ii < 8; ++ii)
                alpha_lds[wg * 8 + ii] = alpha[ii];
        }
        __syncthreads();

        // ---- PV: thread owns output channel c = t ----
        {
            const int c = t;
            #pragma unroll
            for (int ii = 0; ii < 32; ++ii) acc[ii] *= alpha_lds[ii];
            float vreg[64];
            #pragma unroll
            for (int j = 0; j < 64; ++j)
                vreg[j] = v_t[((size_t)b * NPIX + j0 + j) * CCH + c];
            #pragma unroll
            for (int ii = 0; ii < 32; ++ii) {
                float a2 = acc[ii];
                #pragma unroll
                for (int j4 = 0; j4 < 16; ++j4) {
                    float4 pv4 = *(const float4*)&p_lds[ii * 64 + j4 * 4];
                    a2 += pv4.x * vreg[j4 * 4 + 0] + pv4.y * vreg[j4 * 4 + 1]
                        + pv4.z * vreg[j4 * 4 + 2] + pv4.w * vreg[j4 * 4 + 3];
                }
                acc[ii] = a2;
            }
        }
        __syncthreads();   // protect p_lds/alpha_lds for next tile
    }

    // ---- epilogue: divide by l, transpose via LDS, add residual ----
    if (lane == 0) {
        #pragma unroll
        for (int ii = 0; ii < 8; ++ii) l_lds[wg * 8 + ii] = l_i[ii];
    }
    __syncthreads();
    {
        const int c = t;
        #pragma unroll
        for (int ii = 0; ii < 32; ++ii)
            o_lds[c * 33 + ii] = acc[ii] / l_lds[ii];
    }
    __syncthreads();
    {
        const int no = t & 31;
        const int cb = t >> 5;             // 0..7
        #pragma unroll
        for (int r = 0; r < 32; ++r) {
            int cr = r * 8 + cb;
            size_t gidx = ((size_t)b * CCH + cr) * NPIX + i0 + no;
            out[gidx] = o_lds[cr * 33 + no] + x[gidx];
        }
    }
}

extern "C" void kernel_launch(void* const* d_in, const int* in_sizes, int n_in,
                              void* d_out, int out_size, void* d_ws, size_t ws_size,
                              hipStream_t stream) {
    const float* x  = (const float*)d_in[0];
    const float* Wq = (const float*)d_in[1];
    const float* bq = (const float*)d_in[2];
    const float* Wk = (const float*)d_in[3];
    const float* bk = (const float*)d_in[4];
    const float* Wv = (const float*)d_in[5];
    const float* bv = (const float*)d_in[6];
    float* out = (float*)d_out;
    float* ws  = (float*)d_ws;

    float* q_ws = ws;                        // B*DQK*NPIX = 524288 floats
    float* k_ws = ws + 524288;               // 524288 floats
    float* v_t  = ws + 1048576;              // B*NPIX*CCH = 4194304 floats
    // total ws use: ~21 MB

    qk_kernel<<<dim3(16, 4, BATCH), 256, 0, stream>>>(x, Wq, bq, Wk, bk, q_ws, k_ws);
    v_kernel<<<dim3(16, 16, BATCH), 256, 0, stream>>>(x, Wv, bv, v_t);
    attn_kernel<<<dim3(128, BATCH), 256, 0, stream>>>(q_ws, k_ws, v_t, x, out);
}

// Round 2
// 236.652 us; speedup vs baseline: 9.9755x; 9.9755x over previous
//
#include <hip/hip_runtime.h>
#include <math.h>

#define CCH   256
#define NPIX  4096
#define BATCH 4

typedef __attribute__((ext_vector_type(8))) short s16x8;
typedef __attribute__((ext_vector_type(4))) float f32x4;

__device__ __forceinline__ unsigned short f2bf(float f) {
    unsigned int u = __float_as_uint(f);
    u += 0x7fff + ((u >> 16) & 1);          // RNE; inputs are finite
    return (unsigned short)(u >> 16);
}

// ---- fragment-layout address helpers (ushort element index) ----
// q/k frag: lane holds [row16=n%16 in lane&15][k=d: quad*8+dd]
__device__ __forceinline__ size_t qk_addr(int b, int n, int d) {
    return ((((size_t)b * 256 + (n >> 4)) * 64 + ((d >> 3) << 4) + (n & 15)) << 3) + (d & 7);
}
// x frag (B-operand for projections): k = channel c, n = pixel
__device__ __forceinline__ size_t x_addr(int b, int n, int c) {
    return (((((size_t)b * 256 + (n >> 4)) * 8 + (c >> 5)) * 64 + (((c >> 3) & 3) << 4) + (n & 15)) << 3) + (c & 7);
}
// v frag (B-operand for PV): k = pixel j (64-tile, 2 halves of 32), n = channel c
__device__ __forceinline__ size_t v_addr(int b, int n, int c) {
    return ((((((size_t)b * 64 + (n >> 6)) * 16 + (c >> 4)) * 2 + ((n >> 5) & 1)) * 64
             + (((n >> 3) & 3) << 4) + (c & 15)) << 3) + (n & 7);
}

// ---------------- x -> bf16 swizzled B-frag layout ----------------
__global__ __launch_bounds__(256) void cast_kernel(
    const float* __restrict__ x, unsigned short* __restrict__ x_frag)
{
    const int t = threadIdx.x;
    const int b = blockIdx.z;
    const int c0 = blockIdx.y * 64;
    const int n = blockIdx.x * 256 + t;
    const float* xp = x + ((size_t)b * CCH + c0) * NPIX + n;
    #pragma unroll 8
    for (int i = 0; i < 64; ++i) {
        float v = xp[(size_t)i * NPIX];
        x_frag[x_addr(b, n, c0 + i)] = f2bf(v);
    }
}

// ---------------- all projections (q,k,v) via MFMA ----------------
// rows 0..31 = q, 32..63 = k, 64..319 = v. Block: 4 waves x 16 rows, 128 pixels.
__global__ __launch_bounds__(256) void proj_kernel(
    const unsigned short* __restrict__ x_frag,
    const float* __restrict__ Wq, const float* __restrict__ bq,
    const float* __restrict__ Wk, const float* __restrict__ bk,
    const float* __restrict__ Wv, const float* __restrict__ bv,
    unsigned short* __restrict__ q_frag, unsigned short* __restrict__ k_frag,
    unsigned short* __restrict__ v_frag)
{
    const int t = threadIdx.x;
    const int w = t >> 6, lane = t & 63, l15 = lane & 15, quad = lane >> 4;
    const int b = blockIdx.z, rg = blockIdx.y;
    const int n0 = blockIdx.x * 128;
    const int rbase = rg * 64 + w * 16;

    const float *Ws, *bs; unsigned short* dst; int roff; bool isv = false;
    if (rbase < 32)      { Ws = Wq; bs = bq; roff = rbase;      dst = q_frag; }
    else if (rbase < 64) { Ws = Wk; bs = bk; roff = rbase - 32; dst = k_frag; }
    else                 { Ws = Wv; bs = bv; roff = rbase - 64; dst = v_frag; isv = true; }

    // A-frags: W[roff+l15][kb*32 + quad*8 + dd], fp32 -> bf16
    s16x8 af[8];
    const float* wrow = Ws + (size_t)(roff + l15) * CCH + quad * 8;
    #pragma unroll
    for (int kb = 0; kb < 8; ++kb) {
        float4 wa = *(const float4*)(wrow + kb * 32);
        float4 wb = *(const float4*)(wrow + kb * 32 + 4);
        s16x8 a;
        a[0] = (short)f2bf(wa.x); a[1] = (short)f2bf(wa.y);
        a[2] = (short)f2bf(wa.z); a[3] = (short)f2bf(wa.w);
        a[4] = (short)f2bf(wb.x); a[5] = (short)f2bf(wb.y);
        a[6] = (short)f2bf(wb.z); a[7] = (short)f2bf(wb.w);
        af[kb] = a;
    }
    float bias[4];
    #pragma unroll
    for (int rr = 0; rr < 4; ++rr) bias[rr] = bs[roff + quad * 4 + rr];

    #pragma unroll 1
    for (int nt = 0; nt < 8; ++nt) {
        const int ntg = (n0 >> 4) + nt;
        const unsigned short* xb = x_frag + ((((size_t)b * 256 + ntg) * 8) * 64 + lane) * 8;
        f32x4 acc = {0.f, 0.f, 0.f, 0.f};
        #pragma unroll
        for (int kb = 0; kb < 8; ++kb) {
            s16x8 bf = *(const s16x8*)(xb + (size_t)kb * 64 * 8);
            acc = __builtin_amdgcn_mfma_f32_16x16x32_bf16(af[kb], bf, acc, 0, 0, 0);
        }
        const int n = n0 + nt * 16 + l15;
        #pragma unroll
        for (int rr = 0; rr < 4; ++rr) {
            int r = roff + quad * 4 + rr;          // output row within this source
            float val = acc[rr] + bias[rr];
            size_t a = isv ? v_addr(b, n, r) : qk_addr(b, n, r);
            dst[a] = f2bf(val);
        }
    }
}

// ---------------- flash attention, wave-independent, MFMA ----------------
__global__ __launch_bounds__(256) void attn_kernel(
    const unsigned short* __restrict__ q_frag, const unsigned short* __restrict__ k_frag,
    const unsigned short* __restrict__ v_frag, const float* __restrict__ x,
    float* __restrict__ out)
{
    __shared__ unsigned short p_lds[4][16][72];   // per-wave P tile, pad 72 (2-way = free)
    __shared__ float t_lds[4][16][17];            // epilogue transpose tile

    const int t = threadIdx.x;
    const int w = t >> 6, lane = t & 63, l15 = lane & 15, quad = lane >> 4;
    const int b = blockIdx.y;
    const int iw = blockIdx.x * 64 + w * 16;      // this wave's 16 Q rows
    const int it = iw >> 4;

    s16x8 qf = *(const s16x8*)(q_frag + (((size_t)b * 256 + it) * 64 + lane) * 8);

    f32x4 acc[16];
    #pragma unroll
    for (int i = 0; i < 16; ++i) acc[i] = (f32x4){0.f, 0.f, 0.f, 0.f};
    float m_i[4], l_i[4];
    #pragma unroll
    for (int rr = 0; rr < 4; ++rr) { m_i[rr] = -3.4e38f; l_i[rr] = 0.f; }

    const unsigned short* kfb = k_frag + (size_t)b * 256 * 64 * 8 + (size_t)lane * 8;
    const unsigned short* vfb = v_frag + (size_t)b * 64 * 16 * 2 * 64 * 8 + (size_t)lane * 8;
    unsigned short* pw = &p_lds[w][0][0];

    #pragma unroll 1
    for (int jt = 0; jt < 256; jt += 4) {         // 64-col KV tile
        // ---- scores: 4 MFMAs ----
        f32x4 s[4];
        #pragma unroll
        for (int ct = 0; ct < 4; ++ct) {
            s16x8 kf = *(const s16x8*)(kfb + (size_t)(jt + ct) * 64 * 8);
            s[ct] = __builtin_amdgcn_mfma_f32_16x16x32_bf16(qf, kf, (f32x4){0.f,0.f,0.f,0.f}, 0, 0, 0);
        }
        // ---- online softmax (row = quad*4+rr, cols across 16 lanes of quad) ----
        float alpha[4];
        #pragma unroll
        for (int rr = 0; rr < 4; ++rr) {
            float tm = fmaxf(fmaxf(s[0][rr], s[1][rr]), fmaxf(s[2][rr], s[3][rr]));
            tm = fmaxf(tm, __shfl_xor(tm, 1));
            tm = fmaxf(tm, __shfl_xor(tm, 2));
            tm = fmaxf(tm, __shfl_xor(tm, 4));
            tm = fmaxf(tm, __shfl_xor(tm, 8));
            float mn = fmaxf(m_i[rr], tm);
            alpha[rr] = exp2f((m_i[rr] - mn) * 1.44269504f);
            float rs = 0.f;
            #pragma unroll
            for (int ct = 0; ct < 4; ++ct) {
                float p = exp2f((s[ct][rr] - mn) * 1.44269504f);
                s[ct][rr] = p; rs += p;
            }
            rs += __shfl_xor(rs, 1); rs += __shfl_xor(rs, 2);
            rs += __shfl_xor(rs, 4); rs += __shfl_xor(rs, 8);
            l_i[rr] = l_i[rr] * alpha[rr] + rs;
            m_i[rr] = mn;
        }
        // ---- P -> LDS (C/D layout -> A layout round trip, wave-private) ----
        #pragma unroll
        for (int ct = 0; ct < 4; ++ct) {
            #pragma unroll
            for (int rr = 0; rr < 4; ++rr)
                pw[(quad * 4 + rr) * 72 + ct * 16 + l15] = f2bf(s[ct][rr]);
        }
        // ---- rescale accumulator ----
        #pragma unroll
        for (int i = 0; i < 16; ++i) {
            acc[i][0] *= alpha[0]; acc[i][1] *= alpha[1];
            acc[i][2] *= alpha[2]; acc[i][3] *= alpha[3];
        }
        // ---- P A-frags ----
        s16x8 pf0 = *(const s16x8*)(pw + l15 * 72 + quad * 8);
        s16x8 pf1 = *(const s16x8*)(pw + l15 * 72 + 32 + quad * 8);
        // ---- PV: 32 MFMAs over 16 channel tiles ----
        const unsigned short* vt = vfb + (size_t)(jt >> 2) * 16 * 2 * 64 * 8;
        #pragma unroll
        for (int c2 = 0; c2 < 16; ++c2) {
            s16x8 v0 = *(const s16x8*)(vt + (size_t)(c2 * 2 + 0) * 64 * 8);
            s16x8 v1 = *(const s16x8*)(vt + (size_t)(c2 * 2 + 1) * 64 * 8);
            acc[c2] = __builtin_amdgcn_mfma_f32_16x16x32_bf16(pf0, v0, acc[c2], 0, 0, 0);
            acc[c2] = __builtin_amdgcn_mfma_f32_16x16x32_bf16(pf1, v1, acc[c2], 0, 0, 0);
        }
    }

    // ---- epilogue: /l, transpose via LDS, +x, coalesced store ----
    float linv[4];
    #pragma unroll
    for (int rr = 0; rr < 4; ++rr) linv[rr] = 1.f / l_i[rr];
    float* tw = &t_lds[w][0][0];
    #pragma unroll 1
    for (int c2 = 0; c2 < 16; ++c2) {
        #pragma unroll
        for (int rr = 0; rr < 4; ++rr)
            tw[l15 * 17 + quad * 4 + rr] = acc[c2][rr] * linv[rr];
        #pragma unroll
        for (int cc = 0; cc < 4; ++cc) {
            int c = c2 * 16 + cc * 4 + quad;
            float v = tw[(cc * 4 + quad) * 17 + l15];
            size_t idx = ((size_t)b * CCH + c) * NPIX + iw + l15;
            out[idx] = v + x[idx];
        }
    }
}

extern "C" void kernel_launch(void* const* d_in, const int* in_sizes, int n_in,
                              void* d_out, int out_size, void* d_ws, size_t ws_size,
                              hipStream_t stream) {
    const float* x  = (const float*)d_in[0];
    const float* Wq = (const float*)d_in[1];
    const float* bq = (const float*)d_in[2];
    const float* Wk = (const float*)d_in[3];
    const float* bk = (const float*)d_in[4];
    const float* Wv = (const float*)d_in[5];
    const float* bv = (const float*)d_in[6];
    float* out = (float*)d_out;

    unsigned short* ws = (unsigned short*)d_ws;
    unsigned short* x_frag = ws;                   // 4,194,304 ushorts (8 MB)
    unsigned short* q_frag = ws + 4194304;         // 524,288 (1 MB)
    unsigned short* k_frag = ws + 4718592;         // 524,288 (1 MB)
    unsigned short* v_frag = ws + 5242880;         // 4,194,304 (8 MB)  -> 18 MB total

    cast_kernel<<<dim3(16, 4, BATCH), 256, 0, stream>>>(x, x_frag);
    proj_kernel<<<dim3(32, 5, BATCH), 256, 0, stream>>>(x_frag, Wq, bq, Wk, bk, Wv, bv,
                                                        q_frag, k_frag, v_frag);
    attn_kernel<<<dim3(64, BATCH), 256, 0, stream>>>(q_frag, k_frag, v_frag, x, out);
}